// Round 14
// baseline (263.835 us; speedup 1.0000x reference)
//
#include <hip/hip_runtime.h>
#include <hip/hip_fp16.h>

#define NV 100000
#define NE 20000
#define NP 800000
#define DIM 128
#define NEP 20032                    // NE padded to 16-row GEMM blocks

// CSR-build buckets: one reorder-block per bucket, bucket slot-range fits LDS.
#define EB_SH 7
#define EB 128                       // edges per bucket
#define NBKE ((NE + EB - 1) / EB)    // 157
#define ECAP 8192                    // slots per edge bucket (mean 5120, ~43 sigma)
#define VB_SH 8
#define VB 256                       // vertices per bucket
#define NBKV ((NV + VB - 1) / VB)    // 391
#define VCAP 3072                    // slots per vertex bucket (mean 2048, ~22 sigma)

#define PPB 8192                     // pairs per k_part block
#define NPB ((NP + PPB - 1) / PPB)   // 98

typedef unsigned short ushort_t;
typedef short bf16x8 __attribute__((ext_vector_type(8)));
typedef float f32x4 __attribute__((ext_vector_type(4)));

__device__ inline unsigned f2bf(float f) {
    unsigned u = __float_as_uint(f);
    return (u + 0x7fffu + ((u >> 16) & 1u)) >> 16;   // RNE
}
__device__ inline unsigned packbf(float lo, float hi) {
    return f2bf(lo) | (f2bf(hi) << 16);
}
__device__ inline float bflo(unsigned u) { return __uint_as_float(u << 16); }
__device__ inline float bfhi(unsigned u) { return __uint_as_float(u & 0xffff0000u); }

// ---------------- setup kernels ----------------

__device__ inline int wave_scan(int v) {
    int lane = threadIdx.x & 63;
#pragma unroll
    for (int off = 1; off < 64; off <<= 1) {
        int u = __shfl_up(v, off, 64);
        if (lane >= off) v += u;
    }
    return v;
}

// Fused converts + gcur zeroing. Runs FIRST (stream order covers k_part's atomics).
// blocks [0, XB): X fp32 -> bf16; [XB, XB+WB): W transposed hi/lo; [XB+WB]: zero gcur.
#define XB (NV * DIM / 8 / 256)      // 6250
#define WB (3 * DIM * DIM / 256)     // 192
__global__ __launch_bounds__(256) void k_cvtall(const float* __restrict__ X,
                                                ushort_t* __restrict__ Xbf,
                                                const float* __restrict__ Ws,
                                                ushort_t* __restrict__ Wt_hi,
                                                ushort_t* __restrict__ Wt_lo,
                                                int* __restrict__ gcur_e,
                                                int* __restrict__ gcur_v) {
    if (blockIdx.x < XB) {
        int i = blockIdx.x * 256 + threadIdx.x;
        const float4* X4 = (const float4*)X;
        float4 a = X4[(size_t)i * 2];
        float4 b = X4[(size_t)i * 2 + 1];
        uint2 r0, r1;
        r0.x = packbf(a.x, a.y); r0.y = packbf(a.z, a.w);
        r1.x = packbf(b.x, b.y); r1.y = packbf(b.z, b.w);
        ((uint2*)Xbf)[(size_t)i * 2] = r0;
        ((uint2*)Xbf)[(size_t)i * 2 + 1] = r1;
    } else if (blockIdx.x < XB + WB) {
        int idx = (blockIdx.x - XB) * 256 + threadIdx.x;
        int l = idx >> 14;
        int k = (idx >> 7) & 127;
        int c = idx & 127;
        float w = Ws[(size_t)l * 16384 + k * 128 + c];
        unsigned hi = f2bf(w);
        float whi = __uint_as_float(hi << 16);
        unsigned lo = f2bf(w - whi);
        Wt_hi[(size_t)l * 16384 + c * 128 + k] = (ushort_t)hi;
        Wt_lo[(size_t)l * 16384 + c * 128 + k] = (ushort_t)lo;
    } else {
        int t = threadIdx.x;
        if (t < NBKE) gcur_e[t] = 0;
        for (int i = t; i < NBKV; i += 256) gcur_v[i] = 0;
    }
}

// Partition pairs into bucket-grouped staging. 8192 pairs/block so each
// block's per-bucket chunk is >=3 cache lines and written by ONE block.
// stg_e rec: {v:17 | e:15}; stg_v rec: {e:15 | v:17, exp(w)} (un-shifted exp safe: w in [0,1)).
__global__ __launch_bounds__(256) void k_part(const int* __restrict__ pv,
                                              const int* __restrict__ pe,
                                              const float* __restrict__ ew,
                                              int* __restrict__ gcur_e,
                                              int* __restrict__ gcur_v,
                                              unsigned* __restrict__ stg_e,
                                              uint2* __restrict__ stg_v) {
    __shared__ int he[NBKE], hv[NBKV], be[NBKE], bv[NBKV];
    int t = threadIdx.x;
    for (int b = t; b < NBKE; b += 256) he[b] = 0;
    for (int b = t; b < NBKV; b += 256) hv[b] = 0;
    __syncthreads();

    int blk0 = blockIdx.x * PPB;
    for (int it = 0; it < PPB / 1024; ++it) {
        int base = blk0 + it * 1024 + t * 4;
        if (base + 3 < NP) {
            int4 e4 = *(const int4*)(pe + base);
            int4 v4 = *(const int4*)(pv + base);
            atomicAdd(&he[e4.x >> EB_SH], 1);
            atomicAdd(&he[e4.y >> EB_SH], 1);
            atomicAdd(&he[e4.z >> EB_SH], 1);
            atomicAdd(&he[e4.w >> EB_SH], 1);
            atomicAdd(&hv[v4.x >> VB_SH], 1);
            atomicAdd(&hv[v4.y >> VB_SH], 1);
            atomicAdd(&hv[v4.z >> VB_SH], 1);
            atomicAdd(&hv[v4.w >> VB_SH], 1);
        } else {
            for (int k = 0; k < 4 && base + k < NP; ++k) {
                atomicAdd(&he[pe[base + k] >> EB_SH], 1);
                atomicAdd(&hv[pv[base + k] >> VB_SH], 1);
            }
        }
    }
    __syncthreads();
    for (int b = t; b < NBKE; b += 256) {
        int c = he[b];
        be[b] = c ? atomicAdd(&gcur_e[b], c) : 0;
        he[b] = 0;
    }
    for (int b = t; b < NBKV; b += 256) {
        int c = hv[b];
        bv[b] = c ? atomicAdd(&gcur_v[b], c) : 0;
        hv[b] = 0;
    }
    __syncthreads();
    for (int it = 0; it < PPB / 1024; ++it) {
        int base = blk0 + it * 1024 + t * 4;
        int e[4], v[4];
        float w[4];
        int n = 0;
        if (base + 3 < NP) {
            int4 e4 = *(const int4*)(pe + base);
            int4 v4 = *(const int4*)(pv + base);
            float4 w4 = *(const float4*)(ew + base);
            e[0] = e4.x; e[1] = e4.y; e[2] = e4.z; e[3] = e4.w;
            v[0] = v4.x; v[1] = v4.y; v[2] = v4.z; v[3] = v4.w;
            w[0] = w4.x; w[1] = w4.y; w[2] = w4.z; w[3] = w4.w;
            n = 4;
        } else {
            for (int k = 0; base + k < NP && k < 4; ++k) {
                e[n] = pe[base + k]; v[n] = pv[base + k]; w[n] = ew[base + k]; ++n;
            }
        }
        for (int k = 0; k < n; ++k) {
            int b1 = e[k] >> EB_SH;
            int off = be[b1] + atomicAdd(&he[b1], 1);
            if (off < ECAP) stg_e[(size_t)b1 * ECAP + off] = ((unsigned)v[k] << 15) | (unsigned)e[k];
            int b2 = v[k] >> VB_SH;
            int off2 = bv[b2] + atomicAdd(&hv[b2], 1);
            uint2 rec;
            rec.x = ((unsigned)e[k] << 17) | (unsigned)v[k];
            rec.y = __float_as_uint(expf(w[k]));
            if (off2 < VCAP) stg_v[(size_t)b2 * VCAP + off2] = rec;
        }
    }
}

// Merged reorder: blocks [0,NBKE) handle edge buckets; [NBKE, NBKE+NBKV) vertex
// buckets. Each block computes its own bucket base (reduce over gcnt), rebuilds
// per-segment offsets locally, emits eoff/voff, LDS-places records, dumps dense.
__global__ __launch_bounds__(256) void reorder_ev(const unsigned* __restrict__ stg_e,
                                                  const uint2* __restrict__ stg_v,
                                                  const int* __restrict__ gcnt_e,
                                                  const int* __restrict__ gcnt_v,
                                                  int* __restrict__ eoff,
                                                  int* __restrict__ voff,
                                                  int* __restrict__ eslot_v,
                                                  unsigned* __restrict__ vslot) {
    __shared__ int cur[VB];
    __shared__ int wtot[4];
    __shared__ int red[4];
    __shared__ int hist[VB];
    __shared__ int data_e[ECAP];
    __shared__ unsigned data_v[VCAP];
    int t = threadIdx.x;
    int lane = t & 63, wid = t >> 6;

    if (blockIdx.x < NBKE) {
        int b = blockIdx.x;
        int p = (t < b) ? gcnt_e[t] : 0;   // NBKE=157 < 256
#pragma unroll
        for (int off = 32; off > 0; off >>= 1) p += __shfl_down(p, off, 64);
        if (lane == 0) red[wid] = p;
        if (t < EB) hist[t] = 0;
        __syncthreads();
        int base = red[0] + red[1] + red[2] + red[3];
        int lo = b << EB_SH;
        int hi = min(lo + EB, NE);
        int cnt = min(gcnt_e[b], ECAP);
        const unsigned* stg = stg_e + (size_t)b * ECAP;
        for (int i = t; i < cnt; i += 256) {
            atomicAdd(&hist[(int)(stg[i] & 0x7fffu) - lo], 1);
        }
        __syncthreads();
        int v = (t < EB) ? hist[t] : 0;
        int incl = wave_scan(v);
        if (lane == 63) wtot[wid] = incl;
        __syncthreads();
        if (t < EB) {
            int excl = incl - v + (wid == 1 ? wtot[0] : 0);
            cur[t] = excl;
            if (lo + t < hi) eoff[lo + t] = base + excl;
        }
        if (b == NBKE - 1 && t == 0) eoff[NE] = NP;
        __syncthreads();
        for (int i = t; i < cnt; i += 256) {
            unsigned rec = stg[i];
            int e = (int)(rec & 0x7fffu);
            int sl = atomicAdd(&cur[e - lo], 1);
            data_e[sl] = (int)(rec >> 15);
        }
        __syncthreads();
        for (int i = t; i < cnt; i += 256) eslot_v[base + i] = data_e[i];
    } else {
        int b = blockIdx.x - NBKE;
        int p = 0;
        if (t < b) p += gcnt_v[t];
        if (t + 256 < b) p += gcnt_v[t + 256];
#pragma unroll
        for (int off = 32; off > 0; off >>= 1) p += __shfl_down(p, off, 64);
        if (lane == 0) red[wid] = p;
        hist[t] = 0;
        __syncthreads();
        int base = red[0] + red[1] + red[2] + red[3];
        int lo = b << VB_SH;
        int hi = min(lo + VB, NV);
        int cnt = min(gcnt_v[b], VCAP);
        const uint2* stg = stg_v + (size_t)b * VCAP;
        for (int i = t; i < cnt; i += 256) {
            atomicAdd(&hist[(int)(stg[i].x & 0x1ffffu) - lo], 1);
        }
        __syncthreads();
        int v = hist[t];
        int incl = wave_scan(v);
        if (lane == 63) wtot[wid] = incl;
        __syncthreads();
        int add = 0;
        for (int j = 0; j < wid; ++j) add += wtot[j];
        int excl = incl - v + add;
        cur[t] = excl;
        if (lo + t < hi) voff[lo + t] = base + excl;
        if (b == NBKV - 1 && t == 0) voff[NV] = NP;
        __syncthreads();
        for (int i = t; i < cnt; i += 256) {
            uint2 rec = stg[i];
            int vv = (int)(rec.x & 0x1ffffu);
            int sl = atomicAdd(&cur[vv - lo], 1);
            float w = __uint_as_float(rec.y);
            unsigned hw = (unsigned)__half_as_ushort(__float2half(w));
            data_v[sl] = (hw << 16) | (rec.x >> 17);
        }
        __syncthreads();
        for (int i = t; i < cnt; i += 256) vslot[base + i] = data_v[i];
    }
}

// ---------------- per-layer kernels ----------------

__device__ inline void acc8(float* a, uint4 x) {
    a[0] += bflo(x.x); a[1] += bfhi(x.x);
    a[2] += bflo(x.y); a[3] += bfhi(x.y);
    a[4] += bflo(x.z); a[5] += bfhi(x.z);
    a[6] += bflo(x.w); a[7] += bfhi(x.w);
}

__device__ inline void fma8(float* a, float w, uint4 x) {
    a[0] = fmaf(w, bflo(x.x), a[0]); a[1] = fmaf(w, bfhi(x.x), a[1]);
    a[2] = fmaf(w, bflo(x.y), a[2]); a[3] = fmaf(w, bfhi(x.y), a[3]);
    a[4] = fmaf(w, bflo(x.z), a[4]); a[5] = fmaf(w, bfhi(x.z), a[5]);
    a[6] = fmaf(w, bflo(x.w), a[6]); a[7] = fmaf(w, bfhi(x.w), a[7]);
}

// FUSED v2e + GEMM, 512 threads (8 waves) for full per-CU wave residency.
// Phase A: each 32-lane group owns ONE edge (2 halves x 16 j-lanes, 4-deep
//          unroll -> 8 rows of the edge in flight); __shfl_xor(16) combine;
//          exact bf16 hi/lo split to LDS (XOR-swizzled frag index).
// Phase B: 8 waves x 1 col-tile, bf16x3 MFMA (Ahi*Whi + Ahi*Wlo + Alo*Whi).
// Output: bf16 Xe, column-HALF-major [2][NEP][64].
__global__ __launch_bounds__(512) void k_v2e_gemm(const ushort_t* __restrict__ Xbf,
                                                  const int* __restrict__ eslot_v,
                                                  const int* __restrict__ eoff,
                                                  const ushort_t* __restrict__ Wthi,
                                                  const ushort_t* __restrict__ Wtlo,
                                                  const float* __restrict__ bvec,
                                                  ushort_t* __restrict__ Xe) {
    __shared__ uint4 AhiL[16][16];     // [row][frag ^ (row&7)]
    __shared__ uint4 AloL[16][16];
    __shared__ ushort_t eps[16][136];  // epilogue staging (272B rows)
    int tid = threadIdx.x;
    int el = tid >> 5;                 // 0..15 edge within block
    int half = (tid >> 4) & 1;
    int j = tid & 15;
    int eb = blockIdx.x * 16;

    // ---- Phase A: aggregate ----
    {
        int e = eb + el;
        int s = 0, t = 0;
        if (e < NE) { s = eoff[e]; t = eoff[e + 1]; }
        const uint4* Xb = (const uint4*)Xbf;   // 16 uint4 per row
        float a[8] = {0.f, 0.f, 0.f, 0.f, 0.f, 0.f, 0.f, 0.f};
        int i = s + half * 4;
        for (; i + 4 <= t; i += 8) {
            int v0 = eslot_v[i + 0];
            int v1 = eslot_v[i + 1];
            int v2 = eslot_v[i + 2];
            int v3 = eslot_v[i + 3];
            uint4 x0 = Xb[(size_t)v0 * 16 + j];
            uint4 x1 = Xb[(size_t)v1 * 16 + j];
            uint4 x2 = Xb[(size_t)v2 * 16 + j];
            uint4 x3 = Xb[(size_t)v3 * 16 + j];
            acc8(a, x0); acc8(a, x1); acc8(a, x2); acc8(a, x3);
        }
        for (int q = i; q < t && q < i + 4; ++q) {
            uint4 x0 = Xb[(size_t)eslot_v[q] * 16 + j];
            acc8(a, x0);
        }
        // combine the two halves (xor 16 stays inside this edge's 32 lanes)
#pragma unroll
        for (int q = 0; q < 8; ++q) a[q] += __shfl_xor(a[q], 16, 64);
        if (half == 0) {
            float inv = (t > s) ? 1.f / (float)(t - s) : 0.f;
#pragma unroll
            for (int q = 0; q < 8; ++q) a[q] *= inv;
            uint4 h;
            h.x = packbf(a[0], a[1]); h.y = packbf(a[2], a[3]);
            h.z = packbf(a[4], a[5]); h.w = packbf(a[6], a[7]);
            float r0 = a[0] - bflo(h.x), r1 = a[1] - bfhi(h.x);
            float r2 = a[2] - bflo(h.y), r3 = a[3] - bfhi(h.y);
            float r4 = a[4] - bflo(h.z), r5 = a[5] - bfhi(h.z);
            float r6 = a[6] - bflo(h.w), r7 = a[7] - bfhi(h.w);
            uint4 lo4;
            lo4.x = packbf(r0, r1); lo4.y = packbf(r2, r3);
            lo4.z = packbf(r4, r5); lo4.w = packbf(r6, r7);
            int sw = j ^ (el & 7);
            AhiL[el][sw] = h;
            AloL[el][sw] = lo4;
        }
    }
    __syncthreads();

    // ---- Phase B: MFMA, one 16-col tile per wave ----
    int wave = tid >> 6;               // 0..7 = col tile
    int l = tid & 63;
    int r15 = l & 15;
    int kg = (l >> 4) & 3;             // 0..3
    bf16x8 ah[4], al[4];
#pragma unroll
    for (int ks = 0; ks < 4; ++ks) {
        int f = (ks * 4 + kg) ^ (r15 & 7);
        uint4 h4 = AhiL[r15][f];
        uint4 l4 = AloL[r15][f];
        ah[ks] = *(const bf16x8*)&h4;
        al[ks] = *(const bf16x8*)&l4;
    }
    {
        int ct = wave;
        f32x4 c = {0.f, 0.f, 0.f, 0.f};
        size_t bbase = (size_t)(ct * 16 + r15) * 128 + kg * 8;
#pragma unroll
        for (int ks = 0; ks < 4; ++ks) {
            bf16x8 bh = *(const bf16x8*)(Wthi + bbase + ks * 32);
            bf16x8 bl = *(const bf16x8*)(Wtlo + bbase + ks * 32);
            c = __builtin_amdgcn_mfma_f32_16x16x32_bf16(ah[ks], bh, c, 0, 0, 0);
            c = __builtin_amdgcn_mfma_f32_16x16x32_bf16(ah[ks], bl, c, 0, 0, 0);
            c = __builtin_amdgcn_mfma_f32_16x16x32_bf16(al[ks], bh, c, 0, 0, 0);
        }
        float bias = bvec[ct * 16 + r15];
        // C/D layout: col = lane&15, row = (lane>>4)*4 + j   [verified mapping]
#pragma unroll
        for (int q = 0; q < 4; ++q) {
            eps[kg * 4 + q][ct * 16 + r15] = (ushort_t)f2bf(c[q] + bias);
        }
    }
    __syncthreads();

    // ---- dump: 16 rows x 128 cols, 8B per thread (512 threads) ----
    int row = tid >> 5;                // 0..15
    int part = tid & 31;               // 32 x 8B = 256B per row
    const uint2* src = (const uint2*)((const char*)&eps[0][0] + row * 272 + part * 8);
    int rowg = eb + row;
    if (rowg < NE) {
        int h = part >> 4;
        ushort_t* dst = Xe + (size_t)h * NEP * 64 + (size_t)rowg * 64 + (part & 15) * 4;
        *(uint2*)dst = src[0];
    }
}

// X[v,:] = relu( sum w*Xe[e,:] / sum w ), normalization fused, BOTH halves.
// grid NV/32: 32 vertices/block, 8 lanes/vertex; per record gather both halves.
// vslot rec: {fp16(expw):16 | e:16}. 4-record unroll -> 8 loads in flight.
__global__ __launch_bounds__(256) void k_e2v(const ushort_t* __restrict__ Xe,
                                             const unsigned* __restrict__ vslot,
                                             const int* __restrict__ voff,
                                             float* __restrict__ Xout,
                                             ushort_t* __restrict__ Xbf,
                                             int write_bf) {
    int v = blockIdx.x * 32 + (threadIdx.x >> 3);
    int c8 = threadIdx.x & 7;
    int s = voff[v], t = voff[v + 1];
    const uint4* b0 = (const uint4*)Xe;                           // half 0
    const uint4* b1 = (const uint4*)(Xe + (size_t)NEP * 64);      // half 1
    float a[16];
#pragma unroll
    for (int k = 0; k < 16; ++k) a[k] = 0.f;
    float wsum = 0.f;
    int i = s;
    for (; i + 4 <= t; i += 4) {
        unsigned r0 = vslot[i + 0];
        unsigned r1 = vslot[i + 1];
        unsigned r2 = vslot[i + 2];
        unsigned r3 = vslot[i + 3];
        float w0 = __half2float(__ushort_as_half((unsigned short)(r0 >> 16)));
        float w1 = __half2float(__ushort_as_half((unsigned short)(r1 >> 16)));
        float w2 = __half2float(__ushort_as_half((unsigned short)(r2 >> 16)));
        float w3 = __half2float(__ushort_as_half((unsigned short)(r3 >> 16)));
        size_t e0 = (size_t)(r0 & 0xffffu) * 8 + c8;
        size_t e1 = (size_t)(r1 & 0xffffu) * 8 + c8;
        size_t e2 = (size_t)(r2 & 0xffffu) * 8 + c8;
        size_t e3 = (size_t)(r3 & 0xffffu) * 8 + c8;
        uint4 x00 = b0[e0], x01 = b1[e0];
        uint4 x10 = b0[e1], x11 = b1[e1];
        uint4 x20 = b0[e2], x21 = b1[e2];
        uint4 x30 = b0[e3], x31 = b1[e3];
        wsum += (w0 + w1) + (w2 + w3);
        fma8(a, w0, x00); fma8(a + 8, w0, x01);
        fma8(a, w1, x10); fma8(a + 8, w1, x11);
        fma8(a, w2, x20); fma8(a + 8, w2, x21);
        fma8(a, w3, x30); fma8(a + 8, w3, x31);
    }
    for (; i < t; ++i) {
        unsigned r0 = vslot[i];
        float w0 = __half2float(__ushort_as_half((unsigned short)(r0 >> 16)));
        size_t e0 = (size_t)(r0 & 0xffffu) * 8 + c8;
        uint4 x00 = b0[e0], x01 = b1[e0];
        wsum += w0;
        fma8(a, w0, x00); fma8(a + 8, w0, x01);
    }
    float inv = (wsum > 0.f) ? 1.f / wsum : 0.f;
#pragma unroll
    for (int k = 0; k < 16; ++k) a[k] = fmaxf(a[k] * inv, 0.f);
    if (write_bf) {
        uint4 o0, o1;
        o0.x = packbf(a[0], a[1]);  o0.y = packbf(a[2], a[3]);
        o0.z = packbf(a[4], a[5]);  o0.w = packbf(a[6], a[7]);
        o1.x = packbf(a[8], a[9]);  o1.y = packbf(a[10], a[11]);
        o1.z = packbf(a[12], a[13]); o1.w = packbf(a[14], a[15]);
        ((uint4*)Xbf)[(size_t)v * 16 + c8] = o0;
        ((uint4*)Xbf)[(size_t)v * 16 + 8 + c8] = o1;
    } else {
        float4* O = (float4*)Xout;
        O[(size_t)v * 32 + c8 * 2 + 0]  = make_float4(a[0], a[1], a[2], a[3]);
        O[(size_t)v * 32 + c8 * 2 + 1]  = make_float4(a[4], a[5], a[6], a[7]);
        O[(size_t)v * 32 + 16 + c8 * 2] = make_float4(a[8], a[9], a[10], a[11]);
        O[(size_t)v * 32 + 17 + c8 * 2] = make_float4(a[12], a[13], a[14], a[15]);
    }
}

// ---------------- launch ----------------

extern "C" void kernel_launch(void* const* d_in, const int* in_sizes, int n_in,
                              void* d_out, int out_size, void* d_ws, size_t ws_size,
                              hipStream_t stream) {
    const float* X  = (const float*)d_in[0];
    const float* Ws = (const float*)d_in[1];
    const float* bs = (const float*)d_in[2];
    const float* ew = (const float*)d_in[3];
    const int*   pv = (const int*)d_in[4];
    const int*   pe = (const int*)d_in[5];
    float* Xout = (float*)d_out;

    char* p = (char*)d_ws;
    auto take = [&](size_t bytes) {
        char* q = p;
        p += (bytes + 255) & ~(size_t)255;
        return q;
    };
    ushort_t* Xe   = (ushort_t*)take((size_t)2 * NEP * 64 * 2);
    ushort_t* Xbf  = (ushort_t*)take((size_t)NV * DIM * 2);
    ushort_t* Wthi = (ushort_t*)take((size_t)3 * DIM * DIM * 2);
    ushort_t* Wtlo = (ushort_t*)take((size_t)3 * DIM * DIM * 2);
    int*   gcur_e = (int*)take((size_t)NBKE * 4);
    int*   gcur_v = (int*)take((size_t)NBKV * 4);
    int*      eoff    = (int*)take((size_t)(NE + 1) * 4);
    int*      voff    = (int*)take((size_t)(NV + 1) * 4);
    int*      eslot_v = (int*)take((size_t)NP * 4);
    unsigned* vslot   = (unsigned*)take((size_t)NP * 4);
    unsigned* stg_e   = (unsigned*)take((size_t)NBKE * ECAP * 4);
    uint2*    stg_v   = (uint2*)take((size_t)NBKV * VCAP * 8);

    // k_cvtall runs first and zeroes gcur_* (last block) — no memset needed.
    k_cvtall<<<XB + WB + 1, 256, 0, stream>>>(X, Xbf, Ws, Wthi, Wtlo, gcur_e, gcur_v);
    k_part<<<NPB, 256, 0, stream>>>(pv, pe, ew, gcur_e, gcur_v, stg_e, stg_v);
    reorder_ev<<<NBKE + NBKV, 256, 0, stream>>>(stg_e, stg_v, gcur_e, gcur_v,
                                                eoff, voff, eslot_v, vslot);

    for (int l = 0; l < 3; ++l) {
        // row-stochastic aggregation commutes with affine map:
        // Xe = A_v2e @ (Xin @ W + b) == (A_v2e @ Xin) @ W + b
        k_v2e_gemm<<<NEP / 16, 512, 0, stream>>>(Xbf, eslot_v, eoff,
                                                 Wthi + (size_t)l * DIM * DIM,
                                                 Wtlo + (size_t)l * DIM * DIM,
                                                 bs + (size_t)l * DIM, Xe);
        k_e2v<<<NV / 32, 256, 0, stream>>>(Xe, vslot, voff, Xout, Xbf,
                                           (l < 2) ? 1 : 0);
    }
}

// Round 15
// 254.463 us; speedup vs baseline: 1.0368x; 1.0368x over previous
//
#include <hip/hip_runtime.h>
#include <hip/hip_fp16.h>

#define NV 100000
#define NE 20000
#define NP 800000
#define DIM 128
#define NEP 20032                    // NE padded to 16-row GEMM blocks

// CSR-build buckets: one reorder-block per bucket, bucket slot-range fits LDS.
#define EB_SH 7
#define EB 128                       // edges per bucket
#define NBKE ((NE + EB - 1) / EB)    // 157
#define ECAP 8192                    // slots per edge bucket (mean 5120, ~43 sigma)
#define VB_SH 8
#define VB 256                       // vertices per bucket
#define NBKV ((NV + VB - 1) / VB)    // 391
#define VCAP 3072                    // slots per vertex bucket (mean 2048, ~22 sigma)

#define PPB 8192                     // pairs per k_part block
#define NPB ((NP + PPB - 1) / PPB)   // 98

typedef unsigned short ushort_t;
typedef short bf16x8 __attribute__((ext_vector_type(8)));
typedef float f32x4 __attribute__((ext_vector_type(4)));

__device__ inline unsigned f2bf(float f) {
    unsigned u = __float_as_uint(f);
    return (u + 0x7fffu + ((u >> 16) & 1u)) >> 16;   // RNE
}
__device__ inline unsigned packbf(float lo, float hi) {
    return f2bf(lo) | (f2bf(hi) << 16);
}
__device__ inline float bflo(unsigned u) { return __uint_as_float(u << 16); }
__device__ inline float bfhi(unsigned u) { return __uint_as_float(u & 0xffff0000u); }

// ---------------- setup kernels ----------------

__device__ inline int wave_scan(int v) {
    int lane = threadIdx.x & 63;
#pragma unroll
    for (int off = 1; off < 64; off <<= 1) {
        int u = __shfl_up(v, off, 64);
        if (lane >= off) v += u;
    }
    return v;
}

// Fused converts + gcur zeroing. Runs FIRST (stream order covers k_part's atomics).
// blocks [0, XB): X fp32 -> bf16; [XB, XB+WB): W transposed hi/lo; [XB+WB]: zero gcur.
#define XB (NV * DIM / 8 / 256)      // 6250
#define WB (3 * DIM * DIM / 256)     // 192
__global__ __launch_bounds__(256) void k_cvtall(const float* __restrict__ X,
                                                ushort_t* __restrict__ Xbf,
                                                const float* __restrict__ Ws,
                                                ushort_t* __restrict__ Wt_hi,
                                                ushort_t* __restrict__ Wt_lo,
                                                int* __restrict__ gcur_e,
                                                int* __restrict__ gcur_v) {
    if (blockIdx.x < XB) {
        int i = blockIdx.x * 256 + threadIdx.x;
        const float4* X4 = (const float4*)X;
        float4 a = X4[(size_t)i * 2];
        float4 b = X4[(size_t)i * 2 + 1];
        uint2 r0, r1;
        r0.x = packbf(a.x, a.y); r0.y = packbf(a.z, a.w);
        r1.x = packbf(b.x, b.y); r1.y = packbf(b.z, b.w);
        ((uint2*)Xbf)[(size_t)i * 2] = r0;
        ((uint2*)Xbf)[(size_t)i * 2 + 1] = r1;
    } else if (blockIdx.x < XB + WB) {
        int idx = (blockIdx.x - XB) * 256 + threadIdx.x;
        int l = idx >> 14;
        int k = (idx >> 7) & 127;
        int c = idx & 127;
        float w = Ws[(size_t)l * 16384 + k * 128 + c];
        unsigned hi = f2bf(w);
        float whi = __uint_as_float(hi << 16);
        unsigned lo = f2bf(w - whi);
        Wt_hi[(size_t)l * 16384 + c * 128 + k] = (ushort_t)hi;
        Wt_lo[(size_t)l * 16384 + c * 128 + k] = (ushort_t)lo;
    } else {
        int t = threadIdx.x;
        if (t < NBKE) gcur_e[t] = 0;
        for (int i = t; i < NBKV; i += 256) gcur_v[i] = 0;
    }
}

// Partition pairs into bucket-grouped staging. 8192 pairs/block so each
// block's per-bucket chunk is >=3 cache lines and written by ONE block.
// stg_e rec: {v:17 | e:15}; stg_v rec: {e:15 | v:17, exp(w)} (un-shifted exp safe: w in [0,1)).
__global__ __launch_bounds__(256) void k_part(const int* __restrict__ pv,
                                              const int* __restrict__ pe,
                                              const float* __restrict__ ew,
                                              int* __restrict__ gcur_e,
                                              int* __restrict__ gcur_v,
                                              unsigned* __restrict__ stg_e,
                                              uint2* __restrict__ stg_v) {
    __shared__ int he[NBKE], hv[NBKV], be[NBKE], bv[NBKV];
    int t = threadIdx.x;
    for (int b = t; b < NBKE; b += 256) he[b] = 0;
    for (int b = t; b < NBKV; b += 256) hv[b] = 0;
    __syncthreads();

    int blk0 = blockIdx.x * PPB;
    for (int it = 0; it < PPB / 1024; ++it) {
        int base = blk0 + it * 1024 + t * 4;
        if (base + 3 < NP) {
            int4 e4 = *(const int4*)(pe + base);
            int4 v4 = *(const int4*)(pv + base);
            atomicAdd(&he[e4.x >> EB_SH], 1);
            atomicAdd(&he[e4.y >> EB_SH], 1);
            atomicAdd(&he[e4.z >> EB_SH], 1);
            atomicAdd(&he[e4.w >> EB_SH], 1);
            atomicAdd(&hv[v4.x >> VB_SH], 1);
            atomicAdd(&hv[v4.y >> VB_SH], 1);
            atomicAdd(&hv[v4.z >> VB_SH], 1);
            atomicAdd(&hv[v4.w >> VB_SH], 1);
        } else {
            for (int k = 0; k < 4 && base + k < NP; ++k) {
                atomicAdd(&he[pe[base + k] >> EB_SH], 1);
                atomicAdd(&hv[pv[base + k] >> VB_SH], 1);
            }
        }
    }
    __syncthreads();
    for (int b = t; b < NBKE; b += 256) {
        int c = he[b];
        be[b] = c ? atomicAdd(&gcur_e[b], c) : 0;
        he[b] = 0;
    }
    for (int b = t; b < NBKV; b += 256) {
        int c = hv[b];
        bv[b] = c ? atomicAdd(&gcur_v[b], c) : 0;
        hv[b] = 0;
    }
    __syncthreads();
    for (int it = 0; it < PPB / 1024; ++it) {
        int base = blk0 + it * 1024 + t * 4;
        int e[4], v[4];
        float w[4];
        int n = 0;
        if (base + 3 < NP) {
            int4 e4 = *(const int4*)(pe + base);
            int4 v4 = *(const int4*)(pv + base);
            float4 w4 = *(const float4*)(ew + base);
            e[0] = e4.x; e[1] = e4.y; e[2] = e4.z; e[3] = e4.w;
            v[0] = v4.x; v[1] = v4.y; v[2] = v4.z; v[3] = v4.w;
            w[0] = w4.x; w[1] = w4.y; w[2] = w4.z; w[3] = w4.w;
            n = 4;
        } else {
            for (int k = 0; base + k < NP && k < 4; ++k) {
                e[n] = pe[base + k]; v[n] = pv[base + k]; w[n] = ew[base + k]; ++n;
            }
        }
        for (int k = 0; k < n; ++k) {
            int b1 = e[k] >> EB_SH;
            int off = be[b1] + atomicAdd(&he[b1], 1);
            if (off < ECAP) stg_e[(size_t)b1 * ECAP + off] = ((unsigned)v[k] << 15) | (unsigned)e[k];
            int b2 = v[k] >> VB_SH;
            int off2 = bv[b2] + atomicAdd(&hv[b2], 1);
            uint2 rec;
            rec.x = ((unsigned)e[k] << 17) | (unsigned)v[k];
            rec.y = __float_as_uint(expf(w[k]));
            if (off2 < VCAP) stg_v[(size_t)b2 * VCAP + off2] = rec;
        }
    }
}

// Merged reorder: blocks [0,NBKE) handle edge buckets; [NBKE, NBKE+NBKV) vertex
// buckets. Each block computes its own bucket base (reduce over gcnt), rebuilds
// per-segment offsets locally, emits eoff/voff, LDS-places records, dumps dense.
__global__ __launch_bounds__(256) void reorder_ev(const unsigned* __restrict__ stg_e,
                                                  const uint2* __restrict__ stg_v,
                                                  const int* __restrict__ gcnt_e,
                                                  const int* __restrict__ gcnt_v,
                                                  int* __restrict__ eoff,
                                                  int* __restrict__ voff,
                                                  int* __restrict__ eslot_v,
                                                  unsigned* __restrict__ vslot) {
    __shared__ int cur[VB];
    __shared__ int wtot[4];
    __shared__ int red[4];
    __shared__ int hist[VB];
    __shared__ int data_e[ECAP];
    __shared__ unsigned data_v[VCAP];
    int t = threadIdx.x;
    int lane = t & 63, wid = t >> 6;

    if (blockIdx.x < NBKE) {
        int b = blockIdx.x;
        int p = (t < b) ? gcnt_e[t] : 0;   // NBKE=157 < 256
#pragma unroll
        for (int off = 32; off > 0; off >>= 1) p += __shfl_down(p, off, 64);
        if (lane == 0) red[wid] = p;
        if (t < EB) hist[t] = 0;
        __syncthreads();
        int base = red[0] + red[1] + red[2] + red[3];
        int lo = b << EB_SH;
        int hi = min(lo + EB, NE);
        int cnt = min(gcnt_e[b], ECAP);
        const unsigned* stg = stg_e + (size_t)b * ECAP;
        for (int i = t; i < cnt; i += 256) {
            atomicAdd(&hist[(int)(stg[i] & 0x7fffu) - lo], 1);
        }
        __syncthreads();
        int v = (t < EB) ? hist[t] : 0;
        int incl = wave_scan(v);
        if (lane == 63) wtot[wid] = incl;
        __syncthreads();
        if (t < EB) {
            int excl = incl - v + (wid == 1 ? wtot[0] : 0);
            cur[t] = excl;
            if (lo + t < hi) eoff[lo + t] = base + excl;
        }
        if (b == NBKE - 1 && t == 0) eoff[NE] = NP;
        __syncthreads();
        for (int i = t; i < cnt; i += 256) {
            unsigned rec = stg[i];
            int e = (int)(rec & 0x7fffu);
            int sl = atomicAdd(&cur[e - lo], 1);
            data_e[sl] = (int)(rec >> 15);
        }
        __syncthreads();
        for (int i = t; i < cnt; i += 256) eslot_v[base + i] = data_e[i];
    } else {
        int b = blockIdx.x - NBKE;
        int p = 0;
        if (t < b) p += gcnt_v[t];
        if (t + 256 < b) p += gcnt_v[t + 256];
#pragma unroll
        for (int off = 32; off > 0; off >>= 1) p += __shfl_down(p, off, 64);
        if (lane == 0) red[wid] = p;
        hist[t] = 0;
        __syncthreads();
        int base = red[0] + red[1] + red[2] + red[3];
        int lo = b << VB_SH;
        int hi = min(lo + VB, NV);
        int cnt = min(gcnt_v[b], VCAP);
        const uint2* stg = stg_v + (size_t)b * VCAP;
        for (int i = t; i < cnt; i += 256) {
            atomicAdd(&hist[(int)(stg[i].x & 0x1ffffu) - lo], 1);
        }
        __syncthreads();
        int v = hist[t];
        int incl = wave_scan(v);
        if (lane == 63) wtot[wid] = incl;
        __syncthreads();
        int add = 0;
        for (int j = 0; j < wid; ++j) add += wtot[j];
        int excl = incl - v + add;
        cur[t] = excl;
        if (lo + t < hi) voff[lo + t] = base + excl;
        if (b == NBKV - 1 && t == 0) voff[NV] = NP;
        __syncthreads();
        for (int i = t; i < cnt; i += 256) {
            uint2 rec = stg[i];
            int vv = (int)(rec.x & 0x1ffffu);
            int sl = atomicAdd(&cur[vv - lo], 1);
            float w = __uint_as_float(rec.y);
            unsigned hw = (unsigned)__half_as_ushort(__float2half(w));
            data_v[sl] = (hw << 16) | (rec.x >> 17);
        }
        __syncthreads();
        for (int i = t; i < cnt; i += 256) vslot[base + i] = data_v[i];
    }
}

// ---------------- per-layer kernels ----------------

__device__ inline void acc8(float* a, uint4 x) {
    a[0] += bflo(x.x); a[1] += bfhi(x.x);
    a[2] += bflo(x.y); a[3] += bfhi(x.y);
    a[4] += bflo(x.z); a[5] += bfhi(x.z);
    a[6] += bflo(x.w); a[7] += bfhi(x.w);
}

__device__ inline void fma8(float* a, float w, uint4 x) {
    a[0] = fmaf(w, bflo(x.x), a[0]); a[1] = fmaf(w, bfhi(x.x), a[1]);
    a[2] = fmaf(w, bflo(x.y), a[2]); a[3] = fmaf(w, bfhi(x.y), a[3]);
    a[4] = fmaf(w, bflo(x.z), a[4]); a[5] = fmaf(w, bfhi(x.z), a[5]);
    a[6] = fmaf(w, bflo(x.w), a[6]); a[7] = fmaf(w, bfhi(x.w), a[7]);
}

// FUSED v2e + GEMM. Block = 16 edges, 256 threads, grid NEP/16 = 1252.
// (R12 configuration — best measured: 39.5us/dispatch.)
// Phase A: aggregate 16 edges (32 lanes/edge = 2 halves x 16 j-lanes, 4-deep
//          unroll each -> 8 rows in flight; 2 sequential edges per group);
//          __shfl_xor(16) combine; exact bf16 hi/lo split to LDS (XOR-swizzled).
// Phase B: bf16x3 MFMA (Ahi*Whi + Ahi*Wlo + Alo*Whi), 4 waves x 2 col-tiles.
// Output: bf16 Xe, column-HALF-major [2][NEP][64].
__global__ __launch_bounds__(256) void k_v2e_gemm(const ushort_t* __restrict__ Xbf,
                                                  const int* __restrict__ eslot_v,
                                                  const int* __restrict__ eoff,
                                                  const ushort_t* __restrict__ Wthi,
                                                  const ushort_t* __restrict__ Wtlo,
                                                  const float* __restrict__ bvec,
                                                  ushort_t* __restrict__ Xe) {
    __shared__ uint4 AhiL[16][16];     // [row][frag ^ (row&7)]
    __shared__ uint4 AloL[16][16];
    __shared__ ushort_t eps[16][136];  // epilogue staging (272B rows)
    int tid = threadIdx.x;
    int g = tid >> 5;                  // 0..7
    int half = (tid >> 4) & 1;
    int j = tid & 15;
    int eb = blockIdx.x * 16;

    // ---- Phase A: aggregate ----
    for (int k = 0; k < 2; ++k) {
        int el = g * 2 + k;
        int e = eb + el;
        int s = 0, t = 0;
        if (e < NE) { s = eoff[e]; t = eoff[e + 1]; }
        const uint4* Xb = (const uint4*)Xbf;   // 16 uint4 per row
        float a[8] = {0.f, 0.f, 0.f, 0.f, 0.f, 0.f, 0.f, 0.f};
        int i = s + half * 4;
        for (; i + 4 <= t; i += 8) {
            int v0 = eslot_v[i + 0];
            int v1 = eslot_v[i + 1];
            int v2 = eslot_v[i + 2];
            int v3 = eslot_v[i + 3];
            uint4 x0 = Xb[(size_t)v0 * 16 + j];
            uint4 x1 = Xb[(size_t)v1 * 16 + j];
            uint4 x2 = Xb[(size_t)v2 * 16 + j];
            uint4 x3 = Xb[(size_t)v3 * 16 + j];
            acc8(a, x0); acc8(a, x1); acc8(a, x2); acc8(a, x3);
        }
        for (int q = i; q < t && q < i + 4; ++q) {
            uint4 x0 = Xb[(size_t)eslot_v[q] * 16 + j];
            acc8(a, x0);
        }
#pragma unroll
        for (int q = 0; q < 8; ++q) a[q] += __shfl_xor(a[q], 16, 64);
        if (half == 0) {
            float inv = (t > s) ? 1.f / (float)(t - s) : 0.f;
#pragma unroll
            for (int q = 0; q < 8; ++q) a[q] *= inv;
            uint4 h;
            h.x = packbf(a[0], a[1]); h.y = packbf(a[2], a[3]);
            h.z = packbf(a[4], a[5]); h.w = packbf(a[6], a[7]);
            float r0 = a[0] - bflo(h.x), r1 = a[1] - bfhi(h.x);
            float r2 = a[2] - bflo(h.y), r3 = a[3] - bfhi(h.y);
            float r4 = a[4] - bflo(h.z), r5 = a[5] - bfhi(h.z);
            float r6 = a[6] - bflo(h.w), r7 = a[7] - bfhi(h.w);
            uint4 lo4;
            lo4.x = packbf(r0, r1); lo4.y = packbf(r2, r3);
            lo4.z = packbf(r4, r5); lo4.w = packbf(r6, r7);
            int sw = j ^ (el & 7);
            AhiL[el][sw] = h;
            AloL[el][sw] = lo4;
        }
    }
    __syncthreads();

    // ---- Phase B: MFMA ----
    int wave = tid >> 6;
    int l = tid & 63;
    int r15 = l & 15;
    int kg = l >> 4;                    // 0..3
    bf16x8 ah[4], al[4];
#pragma unroll
    for (int ks = 0; ks < 4; ++ks) {
        int f = (ks * 4 + kg) ^ (r15 & 7);
        uint4 h4 = AhiL[r15][f];
        uint4 l4 = AloL[r15][f];
        ah[ks] = *(const bf16x8*)&h4;
        al[ks] = *(const bf16x8*)&l4;
    }
#pragma unroll
    for (int cc = 0; cc < 2; ++cc) {
        int ct = wave * 2 + cc;
        f32x4 c = {0.f, 0.f, 0.f, 0.f};
        size_t bbase = (size_t)(ct * 16 + r15) * 128 + kg * 8;
#pragma unroll
        for (int ks = 0; ks < 4; ++ks) {
            bf16x8 bh = *(const bf16x8*)(Wthi + bbase + ks * 32);
            bf16x8 bl = *(const bf16x8*)(Wtlo + bbase + ks * 32);
            c = __builtin_amdgcn_mfma_f32_16x16x32_bf16(ah[ks], bh, c, 0, 0, 0);
            c = __builtin_amdgcn_mfma_f32_16x16x32_bf16(ah[ks], bl, c, 0, 0, 0);
            c = __builtin_amdgcn_mfma_f32_16x16x32_bf16(al[ks], bh, c, 0, 0, 0);
        }
        float bias = bvec[ct * 16 + r15];
        // C/D layout: col = lane&15, row = (lane>>4)*4 + j   [verified mapping]
#pragma unroll
        for (int q = 0; q < 4; ++q) {
            eps[kg * 4 + q][ct * 16 + r15] = (ushort_t)f2bf(c[q] + bias);
        }
    }
    __syncthreads();

    // ---- dump: 16 rows x 128 cols, 16B per thread ----
    int row = tid >> 4;
    int part = tid & 15;
    const uint4* src = (const uint4*)((const char*)&eps[0][0] + row * 272 + part * 16);
    int rowg = eb + row;
    if (rowg < NE) {
        int h = part >> 3;
        ushort_t* dst = Xe + (size_t)h * NEP * 64 + (size_t)rowg * 64 + (part & 7) * 8;
        *(uint4*)dst = src[0];
    }
}

// X[v,:] = relu( sum w*Xe[e,:] / sum w ), normalization fused, BOTH halves.
// grid NV/32: 32 vertices/block, 8 lanes/vertex; per record gather both halves.
// vslot rec: {fp16(expw):16 | e:16}. 4-record unroll -> 8 loads in flight.
__global__ __launch_bounds__(256) void k_e2v(const ushort_t* __restrict__ Xe,
                                             const unsigned* __restrict__ vslot,
                                             const int* __restrict__ voff,
                                             float* __restrict__ Xout,
                                             ushort_t* __restrict__ Xbf,
                                             int write_bf) {
    int v = blockIdx.x * 32 + (threadIdx.x >> 3);
    int c8 = threadIdx.x & 7;
    int s = voff[v], t = voff[v + 1];
    const uint4* b0 = (const uint4*)Xe;                           // half 0
    const uint4* b1 = (const uint4*)(Xe + (size_t)NEP * 64);      // half 1
    float a[16];
#pragma unroll
    for (int k = 0; k < 16; ++k) a[k] = 0.f;
    float wsum = 0.f;
    int i = s;
    for (; i + 4 <= t; i += 4) {
        unsigned r0 = vslot[i + 0];
        unsigned r1 = vslot[i + 1];
        unsigned r2 = vslot[i + 2];
        unsigned r3 = vslot[i + 3];
        float w0 = __half2float(__ushort_as_half((unsigned short)(r0 >> 16)));
        float w1 = __half2float(__ushort_as_half((unsigned short)(r1 >> 16)));
        float w2 = __half2float(__ushort_as_half((unsigned short)(r2 >> 16)));
        float w3 = __half2float(__ushort_as_half((unsigned short)(r3 >> 16)));
        size_t e0 = (size_t)(r0 & 0xffffu) * 8 + c8;
        size_t e1 = (size_t)(r1 & 0xffffu) * 8 + c8;
        size_t e2 = (size_t)(r2 & 0xffffu) * 8 + c8;
        size_t e3 = (size_t)(r3 & 0xffffu) * 8 + c8;
        uint4 x00 = b0[e0], x01 = b1[e0];
        uint4 x10 = b0[e1], x11 = b1[e1];
        uint4 x20 = b0[e2], x21 = b1[e2];
        uint4 x30 = b0[e3], x31 = b1[e3];
        wsum += (w0 + w1) + (w2 + w3);
        fma8(a, w0, x00); fma8(a + 8, w0, x01);
        fma8(a, w1, x10); fma8(a + 8, w1, x11);
        fma8(a, w2, x20); fma8(a + 8, w2, x21);
        fma8(a, w3, x30); fma8(a + 8, w3, x31);
    }
    for (; i < t; ++i) {
        unsigned r0 = vslot[i];
        float w0 = __half2float(__ushort_as_half((unsigned short)(r0 >> 16)));
        size_t e0 = (size_t)(r0 & 0xffffu) * 8 + c8;
        uint4 x00 = b0[e0], x01 = b1[e0];
        wsum += w0;
        fma8(a, w0, x00); fma8(a + 8, w0, x01);
    }
    float inv = (wsum > 0.f) ? 1.f / wsum : 0.f;
#pragma unroll
    for (int k = 0; k < 16; ++k) a[k] = fmaxf(a[k] * inv, 0.f);
    if (write_bf) {
        uint4 o0, o1;
        o0.x = packbf(a[0], a[1]);  o0.y = packbf(a[2], a[3]);
        o0.z = packbf(a[4], a[5]);  o0.w = packbf(a[6], a[7]);
        o1.x = packbf(a[8], a[9]);  o1.y = packbf(a[10], a[11]);
        o1.z = packbf(a[12], a[13]); o1.w = packbf(a[14], a[15]);
        ((uint4*)Xbf)[(size_t)v * 16 + c8] = o0;
        ((uint4*)Xbf)[(size_t)v * 16 + 8 + c8] = o1;
    } else {
        float4* O = (float4*)Xout;
        O[(size_t)v * 32 + c8 * 2 + 0]  = make_float4(a[0], a[1], a[2], a[3]);
        O[(size_t)v * 32 + c8 * 2 + 1]  = make_float4(a[4], a[5], a[6], a[7]);
        O[(size_t)v * 32 + 16 + c8 * 2] = make_float4(a[8], a[9], a[10], a[11]);
        O[(size_t)v * 32 + 17 + c8 * 2] = make_float4(a[12], a[13], a[14], a[15]);
    }
}

// ---------------- launch ----------------

extern "C" void kernel_launch(void* const* d_in, const int* in_sizes, int n_in,
                              void* d_out, int out_size, void* d_ws, size_t ws_size,
                              hipStream_t stream) {
    const float* X  = (const float*)d_in[0];
    const float* Ws = (const float*)d_in[1];
    const float* bs = (const float*)d_in[2];
    const float* ew = (const float*)d_in[3];
    const int*   pv = (const int*)d_in[4];
    const int*   pe = (const int*)d_in[5];
    float* Xout = (float*)d_out;

    char* p = (char*)d_ws;
    auto take = [&](size_t bytes) {
        char* q = p;
        p += (bytes + 255) & ~(size_t)255;
        return q;
    };
    ushort_t* Xe   = (ushort_t*)take((size_t)2 * NEP * 64 * 2);
    ushort_t* Xbf  = (ushort_t*)take((size_t)NV * DIM * 2);
    ushort_t* Wthi = (ushort_t*)take((size_t)3 * DIM * DIM * 2);
    ushort_t* Wtlo = (ushort_t*)take((size_t)3 * DIM * DIM * 2);
    int*   gcur_e = (int*)take((size_t)NBKE * 4);
    int*   gcur_v = (int*)take((size_t)NBKV * 4);
    int*      eoff    = (int*)take((size_t)(NE + 1) * 4);
    int*      voff    = (int*)take((size_t)(NV + 1) * 4);
    int*      eslot_v = (int*)take((size_t)NP * 4);
    unsigned* vslot   = (unsigned*)take((size_t)NP * 4);
    unsigned* stg_e   = (unsigned*)take((size_t)NBKE * ECAP * 4);
    uint2*    stg_v   = (uint2*)take((size_t)NBKV * VCAP * 8);

    // k_cvtall runs first and zeroes gcur_* (last block) — no memset needed.
    k_cvtall<<<XB + WB + 1, 256, 0, stream>>>(X, Xbf, Ws, Wthi, Wtlo, gcur_e, gcur_v);
    k_part<<<NPB, 256, 0, stream>>>(pv, pe, ew, gcur_e, gcur_v, stg_e, stg_v);
    reorder_ev<<<NBKE + NBKV, 256, 0, stream>>>(stg_e, stg_v, gcur_e, gcur_v,
                                                eoff, voff, eslot_v, vslot);

    for (int l = 0; l < 3; ++l) {
        // row-stochastic aggregation commutes with affine map:
        // Xe = A_v2e @ (Xin @ W + b) == (A_v2e @ Xin) @ W + b
        k_v2e_gemm<<<NEP / 16, 256, 0, stream>>>(Xbf, eslot_v, eoff,
                                                 Wthi + (size_t)l * DIM * DIM,
                                                 Wtlo + (size_t)l * DIM * DIM,
                                                 bs + (size_t)l * DIM, Xe);
        k_e2v<<<NV / 32, 256, 0, stream>>>(Xe, vslot, voff, Xout, Xbf,
                                           (l < 2) ? 1 : 0);
    }
}